// Round 12
// baseline (439.813 us; speedup 1.0000x reference)
//
#include <hip/hip_runtime.h>
#include <hip/hip_bf16.h>

#define N_    64
#define CIN   64
#define COUT  64
#define T_    256
#define V_    25
#define K_    3
#define G_    8
#define D_    192          // K_*COUT
#define TV    6400         // T_*V_
#define P_    409600.0f    // N_*T_*V_

typedef __attribute__((ext_vector_type(8))) short bf16x8;   // 8 bf16 = 4 VGPRs
typedef __attribute__((ext_vector_type(4))) float f32x4;

__device__ __forceinline__ float bf2f(unsigned short u) {
    unsigned int x = ((unsigned int)u) << 16;
    return __uint_as_float(x);
}
__device__ __forceinline__ unsigned short f2bf(float f) {
    unsigned int x = __float_as_uint(f);
    unsigned int lsb = (x >> 16) & 1u;
    x += 0x7fffu + lsb;                 // RNE
    return (unsigned short)(x >> 16);
}
// pack 2 f32 -> 2 bf16 in one dword (RNE), 1 instruction
__device__ __forceinline__ unsigned int cvtpk(float lo, float hi) {
    unsigned int r;
    asm("v_cvt_pk_bf16_f32 %0, %1, %2" : "=v"(r) : "v"(lo), "v"(hi));
    return r;
}

// ---------------------------------------------------------------------------
// K1 (MFMA): z[n,d,tv] = bf16( sum_c x0[n,c,tv]*W[c,d] + bias[d] )
// 3200 blocks = (n, tvb, dh).  Block covers 256 tv x 96 d.  All W-frags
// hoisted to regs (no in-loop loads).  C bounced via LDS -> 128B segments.
// Fused BN0 partial stats -> part[blk][192].
// ---------------------------------------------------------------------------
__global__ __launch_bounds__(256, 3) void k1_mfma(const float* __restrict__ x0,
                                                  const float* __restrict__ W,
                                                  const float* __restrict__ bias,
                                                  unsigned short* __restrict__ z,
                                                  float* __restrict__ part) {
    __shared__ unsigned short zb[4][16 * 68];
    __shared__ float ps[4][6][16], pq[4][6][16];
    int dh   = blockIdx.x & 1;
    int rest = blockIdx.x >> 1;
    int n    = rest / 25;
    int tvb  = rest % 25;
    int tid  = threadIdx.x;
    int wv   = tid >> 6;
    int l    = tid & 63;
    int l15  = l & 15;
    int kg   = l >> 4;
    int wbase = tvb * 256 + wv * 64;
    int d0    = dh * 96;
    const float* xn = x0 + (size_t)n * CIN * TV;

    // A-fragments: x0 -> bf16, 4 m-tiles x 2 kk
    bf16x8 afr[4][2];
#pragma unroll
    for (int m = 0; m < 4; ++m)
#pragma unroll
        for (int kk = 0; kk < 2; ++kk)
#pragma unroll
            for (int h = 0; h < 4; ++h) {
                int c0 = kk * 32 + kg * 8 + 2 * h;
                float f0 = xn[(size_t)c0 * TV + wbase + m * 16 + l15];
                float f1 = xn[(size_t)(c0 + 1) * TV + wbase + m * 16 + l15];
                ((unsigned int*)&afr[m][kk])[h] = cvtpk(f0, f1);
            }

    // W-fragments for this block's 96 d: 6 dt x 2 kk (48 VGPR)
    bf16x8 wfr[6][2];
#pragma unroll
    for (int dt = 0; dt < 6; ++dt)
#pragma unroll
        for (int kk = 0; kk < 2; ++kk)
#pragma unroll
            for (int h = 0; h < 4; ++h) {
                int c0 = kk * 32 + kg * 8 + 2 * h;
                int dcol = d0 + dt * 16 + l15;
                float f0 = W[c0 * D_ + dcol];
                float f1 = W[(c0 + 1) * D_ + dcol];
                ((unsigned int*)&wfr[dt][kk])[h] = cvtpk(f0, f1);
            }

    unsigned short* zn = z + (size_t)n * D_ * TV;
    unsigned short* zw = &zb[wv][0];
#pragma unroll
    for (int dt = 0; dt < 6; ++dt) {
        float bv = bias[d0 + dt * 16 + l15];
        f32x4 acc[4];
#pragma unroll
        for (int m = 0; m < 4; ++m) {
            acc[m][0] = bv; acc[m][1] = bv; acc[m][2] = bv; acc[m][3] = bv;
        }
#pragma unroll
        for (int m = 0; m < 4; ++m) {
            acc[m] = __builtin_amdgcn_mfma_f32_16x16x32_bf16(afr[m][0], wfr[dt][0], acc[m], 0, 0, 0);
            acc[m] = __builtin_amdgcn_mfma_f32_16x16x32_bf16(afr[m][1], wfr[dt][1], acc[m], 0, 0, 0);
        }
        // fused BN0 stats on f32 values
        float s = 0.f, sq = 0.f;
#pragma unroll
        for (int m = 0; m < 4; ++m)
#pragma unroll
            for (int r = 0; r < 4; ++r) { float v = acc[m][r]; s += v; sq += v * v; }
        s  += __shfl_xor(s, 16, 64);  s  += __shfl_xor(s, 32, 64);
        sq += __shfl_xor(sq, 16, 64); sq += __shfl_xor(sq, 32, 64);
        if (kg == 0) { ps[wv][dt][l15] = s; pq[wv][dt][l15] = sq; }
        // bounce C tile through LDS -> coalesced 128B-segment stores
#pragma unroll
        for (int m = 0; m < 4; ++m) {
            uint2 pk;
            pk.x = cvtpk(acc[m][0], acc[m][1]);
            pk.y = cvtpk(acc[m][2], acc[m][3]);
            *(uint2*)(&zw[l15 * 68 + m * 16 + kg * 4]) = pk;
        }
#pragma unroll
        for (int i = 0; i < 4; ++i) {
            int dR  = i * 4 + kg;
            int tvo = l15 * 4;
            uint2 v = *(const uint2*)(&zw[dR * 68 + tvo]);
            *(uint2*)(zn + (size_t)(d0 + dt * 16 + dR) * TV + wbase + tvo) = v;
        }
    }
    __syncthreads();
    if (tid < 96) {
        int dt = tid >> 4, lo = tid & 15;
        float s = ps[0][dt][lo] + ps[1][dt][lo] + ps[2][dt][lo] + ps[3][dt][lo];
        float q = pq[0][dt][lo] + pq[1][dt][lo] + pq[2][dt][lo] + pq[3][dt][lo];
        part[(size_t)blockIdx.x * 192 + tid]      = s;
        part[(size_t)blockIdx.x * 192 + 96 + tid] = q;
    }
}

// ---------------------------------------------------------------------------
// K1c: reduce part[3200][192] -> sum0[192], sumsq0[192].
// blk covers d range via dh: blockIdx of k1 = (n*25+tvb)*2 + dh.
// ---------------------------------------------------------------------------
__global__ __launch_bounds__(64) void k1c_reduce(const float* __restrict__ part,
                                                 float* __restrict__ sum0,
                                                 float* __restrict__ sumsq0) {
    int idx = blockIdx.x;            // 0..383
    int isq = idx >= 192;
    int d   = idx - 192 * isq;
    int dhh = d / 96, dl = d % 96;
    int l = threadIdx.x;
    float s = 0.f;
    for (int tb = l; tb < 1600; tb += 64)
        s += part[(size_t)(tb * 2 + dhh) * 192 + isq * 96 + dl];
#pragma unroll
    for (int off = 32; off > 0; off >>= 1) s += __shfl_down(s, off, 64);
    if (l == 0) {
        if (isq) sumsq0[d] = s; else sum0[d] = s;
    }
}

// ---------------------------------------------------------------------------
// K2 (1 block, light): BN0 affine (a,b), nadj, bconst.
// ---------------------------------------------------------------------------
__global__ __launch_bounds__(256, 1) void k2_prep(const float* __restrict__ A,
                                                  const float* __restrict__ g0,
                                                  const float* __restrict__ b0,
                                                  const float* __restrict__ sum0,
                                                  const float* __restrict__ sumsq0,
                                                  float* a, float* b,
                                                  float* nadj, float* bconst) {
    int tid = threadIdx.x;
    if (tid < D_) {
        float m   = sum0[tid] / P_;
        float var = sumsq0[tid] / P_ - m * m;
        float sc  = g0[tid] * rsqrtf(var + 1e-5f);
        a[tid] = sc;
        b[tid] = b0[tid] - sc * m;
    }
    for (int idx = tid; idx < K_ * G_ * V_; idx += 256) {
        int w  = idx % V_;
        int kg = idx / V_;
        const float* Ap = A + kg * V_ * V_;
        float cs = 0.f;
        for (int v = 0; v < V_; ++v) cs += Ap[v * V_ + w];
        float inv = 1.f / (cs + 1e-3f);
        for (int v = 0; v < V_; ++v) nadj[kg * V_ * V_ + v * V_ + w] = Ap[v * V_ + w] * inv;
    }
    __syncthreads();
    for (int idx = tid; idx < COUT * V_; idx += 256) {
        int c = idx / V_, w = idx % V_, g = c & 7;
        float s = 0.f;
        for (int k = 0; k < K_; ++k) {
            float bk = b[k * COUT + c];
            const float* np_ = nadj + (k * G_ + g) * V_ * V_;
            float cs = 0.f;
            for (int v = 0; v < V_; ++v) cs += np_[v * V_ + w];
            s += bk * cs;
        }
        bconst[idx] = s;
    }
}

// ---------------------------------------------------------------------------
// K3 (MFMA): x2[n,c,t,w] = bconst[c,w] + sum_k sum_v z[n,k64+c,t,v] * (a*nadj)[v,w]
// Block = (n,c), wave owns 64 t.  A = staged z (LDS, wave-private, no barriers);
// B = a[d]*nadj_k bf16 (v padded to 32 w/ zeros; w masked at 25).
// x2 tile bounced via same LDS buffer -> coalesced stores; fused BN2 stats.
// ---------------------------------------------------------------------------
__global__ __launch_bounds__(256, 4) void k3_adj(const unsigned short* __restrict__ z,
                                                 const float* __restrict__ a,
                                                 const float* __restrict__ nadj,
                                                 const float* __restrict__ bconst,
                                                 unsigned short* __restrict__ x2,
                                                 float* __restrict__ sum2,
                                                 float* __restrict__ sumsq2) {
    __shared__ __align__(16) unsigned short buf[4][1600];
    int n = blockIdx.x >> 6;
    int c = blockIdx.x & 63;
    int g = c & 7;
    int tid = threadIdx.x, wv = tid >> 6, l = tid & 63;
    int l15 = l & 15, kg = l >> 4;

    f32x4 acc[4][2];
#pragma unroll
    for (int wt = 0; wt < 2; ++wt) {
        int w = wt * 16 + l15;
        float bc = (w < 25) ? bconst[c * 25 + w] : 0.f;
#pragma unroll
        for (int tt = 0; tt < 4; ++tt) {
            acc[tt][wt][0] = bc; acc[tt][wt][1] = bc;
            acc[tt][wt][2] = bc; acc[tt][wt][3] = bc;
        }
    }

    unsigned short* bw = &buf[wv][0];
#pragma unroll 1
    for (int k = 0; k < K_; ++k) {
        int d = k * 64 + c;
        // stage this wave's 64-t slice (3200B contiguous)
        const uint4* src = (const uint4*)(z + ((size_t)n * D_ + d) * TV + wv * 1600);
        uint4* dst4 = (uint4*)bw;
        for (int e = l; e < 200; e += 64) dst4[e] = src[e];
        // B-frags: a[d] * nadj_k[v][w]  (v = kg*8+j, zero-pad v>=25; w clamped)
        float ad = a[d];
        const float* nb = nadj + (k * 8 + g) * 625;
        bf16x8 bfr[2];
#pragma unroll
        for (int wt = 0; wt < 2; ++wt) {
            int w = wt * 16 + l15;
            int wc = (w < 25) ? w : 0;
#pragma unroll
            for (int h = 0; h < 4; ++h) {
                int v0 = kg * 8 + 2 * h;
                float f0 = (v0     < 25) ? ad * nb[v0 * 25 + wc]       : 0.f;
                float f1 = (v0 + 1 < 25) ? ad * nb[(v0 + 1) * 25 + wc] : 0.f;
                ((unsigned int*)&bfr[wt])[h] = cvtpk(f0, f1);
            }
        }
        // A-frags from LDS + MFMA (same-wave RAW; compiler orders via lgkmcnt)
#pragma unroll
        for (int tt = 0; tt < 4; ++tt) {
            int tl = tt * 16 + l15;
            bf16x8 af;
#pragma unroll
            for (int h = 0; h < 4; ++h) {
                int v0 = kg * 8 + 2 * h;
                unsigned int lo = (v0     < 25) ? (unsigned int)bw[tl * 25 + v0]     : 0u;
                unsigned int hi = (v0 + 1 < 25) ? (unsigned int)bw[tl * 25 + v0 + 1] : 0u;
                ((unsigned int*)&af)[h] = lo | (hi << 16);
            }
            acc[tt][0] = __builtin_amdgcn_mfma_f32_16x16x32_bf16(af, bfr[0], acc[tt][0], 0, 0, 0);
            acc[tt][1] = __builtin_amdgcn_mfma_f32_16x16x32_bf16(af, bfr[1], acc[tt][1], 0, 0, 0);
        }
    }
    // write C into tile (reuse buf), masked w<25
#pragma unroll
    for (int tt = 0; tt < 4; ++tt)
#pragma unroll
        for (int wt = 0; wt < 2; ++wt) {
            int w = wt * 16 + l15;
            if (w < 25) {
#pragma unroll
                for (int r = 0; r < 4; ++r) {
                    int tl = tt * 16 + kg * 4 + r;
                    bw[tl * 25 + w] = f2bf(acc[tt][wt][r]);
                }
            }
        }
    // coalesced copy-out + fused BN2 stats (post-rounding values)
    float s = 0.f, sq = 0.f;
    unsigned short* xb = x2 + ((size_t)n * COUT + c) * TV + wv * 1600;
    for (int e = l; e < 200; e += 64) {
        uint4 vv = ((const uint4*)bw)[e];
        const unsigned short* u = (const unsigned short*)&vv;
#pragma unroll
        for (int i = 0; i < 8; ++i) {
            float f = bf2f(u[i]);
            s += f; sq += f * f;
        }
        ((uint4*)xb)[e] = vv;
    }
#pragma unroll
    for (int off = 32; off > 0; off >>= 1) {
        s  += __shfl_down(s,  off, 64);
        sq += __shfl_down(sq, off, 64);
    }
    if (l == 0) {
        atomicAdd(&sum2[c], s);
        atomicAdd(&sumsq2[c], sq);
    }
}

// ---------------------------------------------------------------------------
// K4: out = relu(BN2(x2) + x0), f32 out.
// ---------------------------------------------------------------------------
__global__ __launch_bounds__(256) void k4_final(const unsigned short* __restrict__ x2,
                                                const float* __restrict__ x0,
                                                const float* __restrict__ g2,
                                                const float* __restrict__ b2,
                                                const float* __restrict__ sum2,
                                                const float* __restrict__ sumsq2,
                                                float* __restrict__ out) {
    const int total4 = N_ * COUT * TV / 4;
    for (int i = blockIdx.x * 256 + threadIdx.x; i < total4; i += gridDim.x * 256) {
        int c = ((i * 4) / TV) & 63;
        float m   = sum2[c] * (1.f / P_);
        float var = sumsq2[c] * (1.f / P_) - m * m;
        float sc  = g2[c] * rsqrtf(var + 1e-5f);
        float sh  = b2[c] - sc * m;
        ushort4 u = ((const ushort4*)x2)[i];
        float4  x = ((const float4*)x0)[i];
        float4 o;
        o.x = fmaxf(sc * bf2f(u.x) + sh + x.x, 0.f);
        o.y = fmaxf(sc * bf2f(u.y) + sh + x.y, 0.f);
        o.z = fmaxf(sc * bf2f(u.z) + sh + x.z, 0.f);
        o.w = fmaxf(sc * bf2f(u.w) + sh + x.w, 0.f);
        ((float4*)out)[i] = o;
    }
}

extern "C" void kernel_launch(void* const* d_in, const int* in_sizes, int n_in,
                              void* d_out, int out_size, void* d_ws, size_t ws_size,
                              hipStream_t stream) {
    const float* x0   = (const float*)d_in[0];
    const float* A    = (const float*)d_in[1];
    const float* W    = (const float*)d_in[2];
    const float* bias = (const float*)d_in[3];
    const float* g0   = (const float*)d_in[4];
    const float* b0   = (const float*)d_in[5];
    const float* g2   = (const float*)d_in[6];
    const float* b2   = (const float*)d_in[7];

    char* ws = (char*)d_ws;
    unsigned short* z  = (unsigned short*)ws;                       // 157,286,400 B
    unsigned short* x2 = (unsigned short*)(ws + 157286400ull);      //  52,428,800 B
    float* part = (float*)x2;   // 3200*192*4 = 2.46 MB, consumed by k1c BEFORE k3 writes x2
    float* fregion = (float*)(ws + 209715200ull);
    float* sum0   = fregion;           // 192
    float* sumsq0 = fregion + 192;     // 192
    float* sum2   = fregion + 384;     // 64
    float* sumsq2 = fregion + 448;     // 64  -> zero 512 floats
    float* a      = fregion + 512;     // 192
    float* b      = a + 192;           // 192
    float* nadj   = b + 192;           // 15000
    float* bconst = nadj + 15000;      // 1600

    hipMemsetAsync(fregion, 0, 512 * sizeof(float), stream);
    k1_mfma<<<3200, 256, 0, stream>>>(x0, W, bias, z, part);
    k1c_reduce<<<384, 64, 0, stream>>>(part, sum0, sumsq0);
    k2_prep<<<1, 256, 0, stream>>>(A, g0, b0, sum0, sumsq0, a, b, nadj, bconst);
    k3_adj<<<4096, 256, 0, stream>>>(z, a, nadj, bconst, x2, sum2, sumsq2);
    k4_final<<<2048, 256, 0, stream>>>(x2, x0, g2, b2, sum2, sumsq2,
                                       (float*)d_out);
}